// Round 2
// 194.254 us; speedup vs baseline: 1.3376x; 1.3376x over previous
//
#include <hip/hip_runtime.h>
#include <math.h>

// Problem constants
#define BDIM 4
#define GDIM 40
#define CDIM 13
#define TDIM 1024
#define FDIM 513                 // T/2 + 1
#define BG   (BDIM*GDIM)         // 160
#define NROW (BG*FDIM)           // 82080 rows of [13] complex
#define NCHUNK 9                 // 9*64 = 576 >= 513 q-rows per bg
#define TK 64                    // K rows staged per LDS tile

typedef _Float16 half4 __attribute__((ext_vector_type(4)));
typedef _Float16 half8 __attribute__((ext_vector_type(8)));
typedef float    f32x4 __attribute__((ext_vector_type(4)));

#define MFMA16(a, b, c) __builtin_amdgcn_mfma_f32_16x16x16f16((a), (b), (c), 0, 0, 0)

__device__ __forceinline__ unsigned bitrev10(unsigned x) { return __brev(x) >> 22; }

// ---------------- Kernel 1: two-for-one rfft(1024) ----------------
__global__ void fft_fwd2(const float* __restrict__ x, float2* __restrict__ xf) {
    __shared__ float re[1024], im[1024];
    const int s2 = blockIdx.x;                   // pair index, 0..1039
    const float* x1 = x + (size_t)(2 * s2) * TDIM;
    const float* x2 = x1 + TDIM;
    for (int t = threadIdx.x; t < 1024; t += blockDim.x) {
        unsigned r = bitrev10(t);
        re[r] = x1[t];
        im[r] = x2[t];
    }
    __syncthreads();
    for (int s = 0; s < 10; ++s) {
        int half = 1 << s;
        for (int j = threadIdx.x; j < 512; j += blockDim.x) {
            int grp = j >> s;
            int pos = j & (half - 1);
            int i1 = (grp << (s + 1)) + pos;
            int i2 = i1 + half;
            float ang = -(float)M_PI * (float)pos / (float)half;
            float sw, cw; __sincosf(ang, &sw, &cw);
            float xr = re[i2], xi = im[i2];
            float tr = cw * xr - sw * xi;
            float ti = cw * xi + sw * xr;
            float ur = re[i1], ui = im[i1];
            re[i1] = ur + tr; im[i1] = ui + ti;
            re[i2] = ur - tr; im[i2] = ui - ti;
        }
        __syncthreads();
    }
    const int sigA = 2 * s2, sigB = sigA + 1;
    const int bgA = sigA / CDIM, cA = sigA % CDIM;
    const int bgB = sigB / CDIM, cB = sigB % CDIM;
    for (int f = threadIdx.x; f < FDIM; f += blockDim.x) {
        int fr = (1024 - f) & 1023;
        float zr = re[f], zi = im[f];
        float wr = re[fr], wi = im[fr];
        xf[((size_t)bgA * FDIM + f) * CDIM + cA] =
            make_float2(0.5f * (zr + wr), 0.5f * (zi - wi));
        xf[((size_t)bgB * FDIM + f) * CDIM + cB] =
            make_float2(0.5f * (zi + wi), 0.5f * (wr - zr));
    }
}

// ---------------- Kernel 2: Q/K/V projections ----------------
// q: float2 rows (for in-reg Q-fragment build in attn).
// KP: per row 64 halves [hi(kr)0..12 | hi(ki)@13..25 | 0 @26..31 | lo(kr)@32..44 | lo(ki)@45..57 | 0 @58..63]
// VT: fp16, transposed: [bg][re/im][c(16)][f stride 520]
__global__ void qkv_kernel(const float2* __restrict__ xf,
                           const float* __restrict__ wq,
                           const float* __restrict__ wk,
                           const float* __restrict__ wv,
                           float2* __restrict__ q,
                           _Float16* __restrict__ KP,
                           _Float16* __restrict__ VT) {
    int gid = blockIdx.x * blockDim.x + threadIdx.x;
    if (gid >= NROW * CDIM) return;
    int r = gid / CDIM;
    int i = gid - r * CDIM;
    const float2* xrow = xf + (size_t)r * CDIM;
    float qr = 0, qi = 0, kr = 0, ki = 0, vr = 0, vi = 0;
#pragma unroll
    for (int c = 0; c < CDIM; ++c) {
        float2 xc = xrow[c];
        float a = wq[c * CDIM + i]; qr += xc.x * a; qi += xc.y * a;
        float b = wk[c * CDIM + i]; kr += xc.x * b; ki += xc.y * b;
        float d = wv[c * CDIM + i]; vr += xc.x * d; vi += xc.y * d;
    }
    q[gid] = make_float2(qr, qi);

    _Float16* krow = KP + (size_t)r * 64;
    _Float16 h0 = (_Float16)kr;
    _Float16 h1 = (_Float16)ki;
    krow[i]      = h0;
    krow[13 + i] = h1;
    krow[32 + i] = (_Float16)(kr - (float)h0);
    krow[45 + i] = (_Float16)(ki - (float)h1);
    if (i == 12) {   // zero the pad halves 26..31 and 58..63
        *(unsigned int*)(krow + 26) = 0u;
        *(unsigned int*)(krow + 28) = 0u;
        *(unsigned int*)(krow + 30) = 0u;
        *(unsigned int*)(krow + 58) = 0u;
        *(unsigned int*)(krow + 60) = 0u;
        *(unsigned int*)(krow + 62) = 0u;
    }
    int bg = r / FDIM;
    int f  = r - bg * FDIM;
    VT[((size_t)(bg * 2 + 0) * 16 + i) * 520 + f] = (_Float16)vr;
    VT[((size_t)(bg * 2 + 1) * 16 + i) * 520 + f] = (_Float16)vi;
}

// ---------------- Kernel 3: MFMA flash attention ----------------
// Block = 4 waves; wave w owns 16 q-rows (frow = chunk*64 + w*16 + lane&15).
// Scores: swapped-operand mfma_f32_16x16x16f16, A = K-rows (fp16 hi/lo from LDS),
// B = Q-rows (fp16 hi/lo, in registers).
//   Reference computes plain product q.k (NO conjugation):
//     Re = sum qr*kr - qi*ki   -> u  = [qr, -qi] . w,  w = [kr, ki]
//     Im = sum qr*ki + qi*kr   -> u' = [qi,  qr] . w
// Score D layout: q = lane&15, kidx = 4*(lane>>4)+reg  ==  PV B-fragment layout.
// PV: A = V^T tile (fp16), B = P, D rows = channel c = 4*(lane>>4)+reg.
__global__ __launch_bounds__(256, 4) void attn_kernel(const float2* __restrict__ q,
                                                      const _Float16* __restrict__ KP,
                                                      const _Float16* __restrict__ VT,
                                                      float2* __restrict__ outspec) {
    __shared__ __align__(16) _Float16 Klds[TK * 64];        // 8 KB, XOR-swizzled 16B granules
    __shared__ __align__(16) _Float16 VTlds[2 * 16 * 72];   // 4.6 KB, c-stride 72 halves

    const int bg    = blockIdx.x / NCHUNK;
    const int chunk = blockIdx.x % NCHUNK;
    const int tid   = threadIdx.x;
    const int w     = tid >> 6;
    const int lane  = tid & 63;
    const int qlane = lane & 15;
    const int g     = lane >> 4;
    const int frow  = chunk * 64 + w * 16 + qlane;
    const bool writer = (frow < FDIM);
    const int f     = writer ? frow : (FDIM - 1);
    const size_t rowbase = (size_t)(bg * FDIM + f) * CDIM;

    // ---- build Q fragments in registers: u = [qr,-qi], u' = [qi,qr], hi/lo split ----
    half4 uh[2], ul[2], u2h[2], u2l[2];
#pragma unroll
    for (int c01 = 0; c01 < 2; ++c01) {
#pragma unroll
        for (int j = 0; j < 4; ++j) {
            int k = c01 * 16 + 4 * g + j;
            float a = 0.f, b = 0.f;
            if (k < CDIM) {
                float2 t = q[rowbase + k];          a = t.x;  b = t.y;
            } else if (k < 2 * CDIM) {
                float2 t = q[rowbase + (k - CDIM)]; a = -t.y; b = t.x;
            }
            _Float16 ah = (_Float16)a;
            uh[c01][j]  = ah;
            ul[c01][j]  = (_Float16)(a - (float)ah);
            _Float16 bh = (_Float16)b;
            u2h[c01][j] = bh;
            u2l[c01][j] = (_Float16)(b - (float)bh);
        }
    }

    f32x4 o_re = {0.f, 0.f, 0.f, 0.f};
    f32x4 o_im = {0.f, 0.f, 0.f, 0.f};
    float m = -INFINITY, l = 0.f;

    const _Float16* __restrict__ KPg = KP + (size_t)bg * FDIM * 64;
    const _Float16* __restrict__ VTg = VT + (size_t)bg * 2 * 16 * 520;

    for (int t0 = 0; t0 < FDIM; t0 += TK) {          // 9 tiles of 64 K-rows
        __syncthreads();                             // previous tile fully consumed
        // ---- stage K rows (2 x 16B granules per thread, XOR-swizzled placement) ----
#pragma unroll
        for (int hh = 0; hh < 2; ++hh) {
            int gr  = tid + hh * 256;                // 0..511
            int krw = gr >> 3, gg = gr & 7;
            half8 val;
#pragma unroll
            for (int e = 0; e < 8; ++e) val[e] = (_Float16)0.f;
            int grow = t0 + krw;
            if (grow < FDIM)
                val = *(const half8*)(KPg + (size_t)grow * 64 + gg * 8);
            *(half8*)(Klds + krw * 64 + ((gg ^ (krw & 7)) << 3)) = val;
        }
        // ---- stage V^T (1 x 16B granule per thread) ----
        {
            int gk = tid & 7, cc = (tid >> 3) & 15, part = tid >> 7;
            int rb = t0 + gk * 8;
            half8 val;
#pragma unroll
            for (int e = 0; e < 8; ++e) val[e] = (_Float16)0.f;
            if (rb < FDIM) {
                val = *(const half8*)(VTg + ((size_t)(part * 16 + cc)) * 520 + rb);
                if (rb + 8 > FDIM) {                 // straddle: zero tail (keeps 0*p, no NaN)
#pragma unroll
                    for (int e = 0; e < 8; ++e) if (rb + e >= FDIM) val[e] = (_Float16)0.f;
                }
            }
            *(half8*)(VTlds + (part * 16 + cc) * 72 + gk * 8) = val;
        }
        __syncthreads();

        // ---- 4 sub-tiles of 16 keys ----
#pragma unroll
        for (int sub = 0; sub < 4; ++sub) {
            const int arow = sub * 16 + qlane;       // K-row supplied by this lane (A-frag m)
            const int rx   = arow & 7;
            const _Float16* kr = Klds + arow * 64;
#define KFRAG(h) (*(const half4*)(kr + (((((h) >> 3)) ^ rx) << 3) + ((h) & 7)))
            half4 wh0 = KFRAG(4 * g);
            half4 wh1 = KFRAG(16 + 4 * g);
            half4 wl0 = KFRAG(32 + 4 * g);
            half4 wl1 = KFRAG(48 + 4 * g);
#undef KFRAG
            f32x4 sre = {0.f, 0.f, 0.f, 0.f};
            f32x4 sim = {0.f, 0.f, 0.f, 0.f};
            sre = MFMA16(wh0, uh[0], sre);
            sre = MFMA16(wh1, uh[1], sre);
            sre = MFMA16(wl0, uh[0], sre);
            sre = MFMA16(wl1, uh[1], sre);
            sre = MFMA16(wh0, ul[0], sre);
            sre = MFMA16(wh1, ul[1], sre);
            sre = MFMA16(wl0, ul[0], sre);           // ll term: keeps score err at fp32 level
            sre = MFMA16(wl1, ul[1], sre);
            sim = MFMA16(wh0, u2h[0], sim);
            sim = MFMA16(wh1, u2h[1], sim);
            sim = MFMA16(wl0, u2h[0], sim);
            sim = MFMA16(wl1, u2h[1], sim);
            sim = MFMA16(wh0, u2l[0], sim);
            sim = MFMA16(wh1, u2l[1], sim);
            sim = MFMA16(wl0, u2l[0], sim);
            sim = MFMA16(wl1, u2l[1], sim);

            // |score| ; this lane holds scores for its q at kidx = sub*16 + 4g + j
            float s0 = sqrtf(fmaf(sre[0], sre[0], sim[0] * sim[0]));
            float s1 = sqrtf(fmaf(sre[1], sre[1], sim[1] * sim[1]));
            float s2 = sqrtf(fmaf(sre[2], sre[2], sim[2] * sim[2]));
            float s3 = sqrtf(fmaf(sre[3], sre[3], sim[3] * sim[3]));
            float tmax = fmaxf(fmaxf(s0, s1), fmaxf(s2, s3));
            tmax = fmaxf(tmax, __shfl_xor(tmax, 16));
            tmax = fmaxf(tmax, __shfl_xor(tmax, 32));
            float mnew  = fmaxf(m, tmax);
            float alpha = __expf(m - mnew);          // exp(-inf)=0 covers first tile
            m = mnew;
            l *= alpha;
            o_re *= alpha;
            o_im *= alpha;
            float p0 = __expf(s0 - m);
            float p1 = __expf(s1 - m);
            float p2 = __expf(s2 - m);
            float p3 = __expf(s3 - m);
            l += (p0 + p1) + (p2 + p3);
            half4 pk;
            pk[0] = (_Float16)p0; pk[1] = (_Float16)p1;
            pk[2] = (_Float16)p2; pk[3] = (_Float16)p3;

            const int voff = sub * 16 + 4 * g;
            half4 vfr = *(const half4*)(VTlds + qlane * 72 + voff);
            half4 vfi = *(const half4*)(VTlds + (16 + qlane) * 72 + voff);
            o_re = MFMA16(vfr, pk, o_re);
            o_im = MFMA16(vfi, pk, o_im);
        }
    }

    // ---- merge partial l across the 4 k-groups of each q-column ----
    l += __shfl_xor(l, 16);
    l += __shfl_xor(l, 32);
    if (writer) {
        float inv = 1.f / l;
#pragma unroll
        for (int j = 0; j < 4; ++j) {
            int c = 4 * g + j;                       // D row = channel
            if (c < CDIM)
                outspec[((size_t)(bg * CDIM + c)) * FDIM + frow] =
                    make_float2(o_re[j] * inv, o_im[j] * inv);
        }
    }
}

// ---------------- Kernel 4: two-for-one irfft(1024) ----------------
__global__ void fft_inv2(const float2* __restrict__ spec, float* __restrict__ out) {
    __shared__ float re[1024], im[1024];
    const int s2 = blockIdx.x;                   // pair 0..1039
    const float2* Y1 = spec + (size_t)(2 * s2) * FDIM;
    const float2* Y2 = Y1 + FDIM;
    for (int t = threadIdx.x; t < 1024; t += blockDim.x) {
        float a, b, c, d;
        if (t <= 512) {
            float2 y1 = Y1[t], y2 = Y2[t];
            bool edge = (t == 0) | (t == 512);
            a = y1.x; b = edge ? 0.f : y1.y;
            c = y2.x; d = edge ? 0.f : y2.y;
        } else {
            float2 y1 = Y1[1024 - t], y2 = Y2[1024 - t];
            a = y1.x; b = -y1.y;
            c = y2.x; d = -y2.y;
        }
        unsigned r = bitrev10(t);
        re[r] = a - d;
        im[r] = b + c;
    }
    __syncthreads();
    for (int s = 0; s < 10; ++s) {
        int half = 1 << s;
        for (int j = threadIdx.x; j < 512; j += blockDim.x) {
            int grp = j >> s;
            int pos = j & (half - 1);
            int i1 = (grp << (s + 1)) + pos;
            int i2 = i1 + half;
            float ang = (float)M_PI * (float)pos / (float)half;   // +sign = inverse
            float sw, cw; __sincosf(ang, &sw, &cw);
            float xr = re[i2], xi = im[i2];
            float tr = cw * xr - sw * xi;
            float ti = cw * xi + sw * xr;
            float ur = re[i1], ui = im[i1];
            re[i1] = ur + tr; im[i1] = ui + ti;
            re[i2] = ur - tr; im[i2] = ui - ti;
        }
        __syncthreads();
    }
    const float scale = 1.0f / 1024.0f;
    float* o1 = out + (size_t)(2 * s2) * TDIM;
    for (int t = threadIdx.x; t < 1024; t += blockDim.x) {
        o1[t]        = re[t] * scale;
        o1[TDIM + t] = im[t] * scale;
    }
}

extern "C" void kernel_launch(void* const* d_in, const int* in_sizes, int n_in,
                              void* d_out, int out_size, void* d_ws, size_t ws_size,
                              hipStream_t stream) {
    const float* x  = (const float*)d_in[0];
    const float* wq = (const float*)d_in[1];
    const float* wk = (const float*)d_in[2];
    const float* wv = (const float*)d_in[3];
    float* out = (float*)d_out;

    const size_t n = (size_t)NROW * CDIM;        // 1,067,040 complex per buffer
    float2* xf = (float2*)d_ws;                  // x_fft, later reused as out-spectrum
    float2* q  = xf + n;                         // 8.54 MB
    _Float16* KP = (_Float16*)(q + n);           // NROW*64 halves = 10.51 MB
    _Float16* VT = KP + (size_t)NROW * 64;       // BG*2*16*520 halves = 5.32 MB (total 32.9 MB)

    fft_fwd2<<<BG * CDIM / 2, 256, 0, stream>>>(x, xf);
    qkv_kernel<<<(NROW * CDIM + 255) / 256, 256, 0, stream>>>(xf, wq, wk, wv, q, KP, VT);
    attn_kernel<<<BG * NCHUNK, 256, 0, stream>>>(q, KP, VT, xf /* outspec, aliases xf */);
    fft_inv2<<<BG * CDIM / 2, 256, 0, stream>>>(xf, out);
}